// Round 2
// baseline (16123.421 us; speedup 1.0000x reference)
//
#include <hip/hip_runtime.h>
#include <stdint.h>

#define NN 100000
#define DF 128
#define NE 3200000
#define NELEM (NN * DF)          // 12,800,000
// SCHEME 0: partitionable, bits = out0 ^ out1   (current JAX default; fixed combine)
// SCHEME 1: partitionable, bits = out1          (round-1 guess — WRONG, absmax 92.8)
// SCHEME 2: legacy iota split-in-half
#define SCHEME 0

// ---------------- Threefry-2x32 (JAX-exact) ----------------
__host__ __device__ __forceinline__ void tf2x32(uint32_t& x0, uint32_t& x1,
                                                uint32_t k0, uint32_t k1) {
  uint32_t ks2 = k0 ^ k1 ^ 0x1BD11BDAu;
  x0 += k0; x1 += k1;
#define TF_RND(r) { x0 += x1; x1 = (x1 << (r)) | (x1 >> (32 - (r))); x1 ^= x0; }
  TF_RND(13) TF_RND(15) TF_RND(26) TF_RND(6)
  x0 += k1;  x1 += ks2 + 1u;
  TF_RND(17) TF_RND(29) TF_RND(16) TF_RND(24)
  x0 += ks2; x1 += k0 + 2u;
  TF_RND(13) TF_RND(15) TF_RND(26) TF_RND(6)
  x0 += k0;  x1 += k1 + 3u;
  TF_RND(17) TF_RND(29) TF_RND(16) TF_RND(24)
  x0 += k1;  x1 += ks2 + 4u;
  TF_RND(13) TF_RND(15) TF_RND(26) TF_RND(6)
  x0 += ks2; x1 += k0 + 5u;
#undef TF_RND
}

__device__ __forceinline__ bool keep_elem(uint32_t kA, uint32_t kB, uint32_t idx) {
#if SCHEME == 0
  uint32_t x0 = 0u, x1 = idx;          // counter = (hi=0, lo=i)
  tf2x32(x0, x1, kA, kB);
  uint32_t bits = x0 ^ x1;             // partitionable 32-bit combine
#elif SCHEME == 1
  uint32_t x0 = 0u, x1 = idx;
  tf2x32(x0, x1, kA, kB);
  uint32_t bits = x1;
#else
  const uint32_t half = NELEM / 2;
  uint32_t x0, x1;
  bool lo = idx < half;
  x0 = lo ? idx : idx - half;
  x1 = lo ? idx + half : idx;
  tf2x32(x0, x1, kA, kB);
  uint32_t bits = lo ? x0 : x1;
#endif
  float u = __uint_as_float((bits >> 9) | 0x3f800000u) - 1.0f;
  return u < 0.9f;
}

// ---------------- Kernels ----------------
__global__ __launch_bounds__(256) void init_kernel(const float4* __restrict__ q,
                                                   float4* __restrict__ prev,
                                                   float4* __restrict__ acc,
                                                   float4* __restrict__ S) {
  int i = blockIdx.x * 256 + threadIdx.x;
  if (i < NELEM / 4) {
    float4 v = q[i];
    prev[i] = v;
    acc[i]  = v;
    S[i]    = make_float4(0.f, 0.f, 0.f, 0.f);
  }
}

// one edge per 32 lanes; each lane handles a float4 (128 floats / edge)
__global__ __launch_bounds__(256) void scatter_kernel(const int* __restrict__ rows,
                                                      const int* __restrict__ cols,
                                                      const float* __restrict__ vals,
                                                      const float* __restrict__ x,
                                                      float* __restrict__ S) {
  int lane = threadIdx.x & 31;
  int e = blockIdx.x * 8 + (threadIdx.x >> 5);
  if (e >= NE) return;
  int r = rows[e];
  int c = cols[e];
  float v = vals[e];
  const float4* xr = reinterpret_cast<const float4*>(x + (size_t)c * DF);
  float4 xv = xr[lane];
  float* o = S + (size_t)r * DF + lane * 4;
  unsafeAtomicAdd(o + 0, xv.x * v);
  unsafeAtomicAdd(o + 1, xv.y * v);
  unsafeAtomicAdd(o + 2, xv.z * v);
  unsafeAtomicAdd(o + 3, xv.w * v);
}

template <bool LAST>
__global__ __launch_bounds__(256) void layer_kernel(float4* __restrict__ S,
                                                    float4* __restrict__ prev,
                                                    float4* __restrict__ acc,
                                                    uint32_t kA, uint32_t kB) {
  int i = blockIdx.x * 256 + threadIdx.x;
  if (i >= NELEM / 4) return;
  float4 s = S[i];
  float4 p = prev[i];
  float4 a = acc[i];
  uint32_t base = (uint32_t)i * 4u;
  float sv[4] = {s.x, s.y, s.z, s.w};
  float pv[4] = {p.x, p.y, p.z, p.w};
  float h[4];
#pragma unroll
  for (int j = 0; j < 4; ++j) {
    float t = sv[j] + pv[j];
    h[j] = keep_elem(kA, kB, base + (uint32_t)j) ? t * (1.0f / 0.9f) : 0.0f;
  }
  a.x += h[0]; a.y += h[1]; a.z += h[2]; a.w += h[3];
  if (LAST) { a.x *= 0.25f; a.y *= 0.25f; a.z *= 0.25f; a.w *= 0.25f; }
  acc[i]  = a;
  prev[i] = make_float4(h[0], h[1], h[2], h[3]);
  S[i]    = make_float4(0.f, 0.f, 0.f, 0.f);  // ready for next layer's scatter
}

// ---------------- Launch ----------------
extern "C" void kernel_launch(void* const* d_in, const int* in_sizes, int n_in,
                              void* d_out, int out_size, void* d_ws, size_t ws_size,
                              hipStream_t stream) {
  const float* q   = (const float*)d_in[0];
  const int* rows  = (const int*)d_in[1];
  const int* cols  = (const int*)d_in[2];
  const float* vls = (const float*)d_in[3];
  float* acc  = (float*)d_out;
  float* prev = (float*)d_ws;
  float* S    = prev + NELEM;

  // layer keys: fold_in(key(42), layer) = threefry2x32((0,42),(0,layer))
  uint32_t kA[3], kB[3];
  for (int l = 0; l < 3; ++l) {
    uint32_t x0 = 0u, x1 = (uint32_t)l;
    tf2x32(x0, x1, 0u, 42u);
    kA[l] = x0; kB[l] = x1;
  }

  dim3 blk(256);
  init_kernel<<<NELEM / 4 / 256, blk, 0, stream>>>(
      (const float4*)q, (float4*)prev, (float4*)acc, (float4*)S);

  for (int l = 0; l < 3; ++l) {
    scatter_kernel<<<NE / 8, blk, 0, stream>>>(rows, cols, vls, prev, S);
    if (l < 2)
      layer_kernel<false><<<NELEM / 4 / 256, blk, 0, stream>>>(
          (float4*)S, (float4*)prev, (float4*)acc, kA[l], kB[l]);
    else
      layer_kernel<true><<<NELEM / 4 / 256, blk, 0, stream>>>(
          (float4*)S, (float4*)prev, (float4*)acc, kA[l], kB[l]);
  }
}

// Round 3
// 1284.518 us; speedup vs baseline: 12.5521x; 12.5521x over previous
//
#include <hip/hip_runtime.h>
#include <stdint.h>

#define NN 100000
#define DF 128
#define NE 3200000
#define NELEM (NN * DF)          // 12,800,000

// ---------------- Threefry-2x32 (JAX-exact, partitionable, bits = x0^x1) ----
__host__ __device__ __forceinline__ void tf2x32(uint32_t& x0, uint32_t& x1,
                                                uint32_t k0, uint32_t k1) {
  uint32_t ks2 = k0 ^ k1 ^ 0x1BD11BDAu;
  x0 += k0; x1 += k1;
#define TF_RND(r) { x0 += x1; x1 = (x1 << (r)) | (x1 >> (32 - (r))); x1 ^= x0; }
  TF_RND(13) TF_RND(15) TF_RND(26) TF_RND(6)
  x0 += k1;  x1 += ks2 + 1u;
  TF_RND(17) TF_RND(29) TF_RND(16) TF_RND(24)
  x0 += ks2; x1 += k0 + 2u;
  TF_RND(13) TF_RND(15) TF_RND(26) TF_RND(6)
  x0 += k0;  x1 += k1 + 3u;
  TF_RND(17) TF_RND(29) TF_RND(16) TF_RND(24)
  x0 += k1;  x1 += ks2 + 4u;
  TF_RND(13) TF_RND(15) TF_RND(26) TF_RND(6)
  x0 += ks2; x1 += k0 + 5u;
#undef TF_RND
}

__device__ __forceinline__ bool keep_elem(uint32_t kA, uint32_t kB, uint32_t idx) {
  uint32_t x0 = 0u, x1 = idx;          // counter = (hi=0, lo=i)
  tf2x32(x0, x1, kA, kB);
  uint32_t bits = x0 ^ x1;             // partitionable 32-bit combine (verified r2)
  float u = __uint_as_float((bits >> 9) | 0x3f800000u) - 1.0f;
  return u < 0.9f;
}

// ======================= CSR build =======================
__global__ __launch_bounds__(256) void zero_cnt_kernel(int* __restrict__ cnt) {
  int i = blockIdx.x * 256 + threadIdx.x;
  if (i < NN) cnt[i] = 0;
}

__global__ __launch_bounds__(256) void hist_kernel(const int* __restrict__ rows,
                                                   int* __restrict__ cnt) {
  int e = blockIdx.x * 256 + threadIdx.x;
  if (e < NE) atomicAdd(&cnt[rows[e]], 1);
}

// single-block exclusive scan over NN counts -> row_ptr, row_fill; row_ptr[NN]=NE
__global__ __launch_bounds__(1024) void scan_kernel(const int* __restrict__ cnt,
                                                    int* __restrict__ row_ptr,
                                                    int* __restrict__ row_fill) {
  __shared__ int lds[1024];
  __shared__ int carry_s;
  int tid = threadIdx.x;
  if (tid == 0) carry_s = 0;
  __syncthreads();
  for (int base = 0; base < NN; base += 1024) {
    int i = base + tid;
    int v = (i < NN) ? cnt[i] : 0;
    lds[tid] = v;
    __syncthreads();
    for (int off = 1; off < 1024; off <<= 1) {   // inclusive Hillis-Steele
      int add = (tid >= off) ? lds[tid - off] : 0;
      __syncthreads();
      lds[tid] += add;
      __syncthreads();
    }
    int incl = lds[tid];
    int carry = carry_s;
    if (i < NN) {
      int excl = carry + incl - v;
      row_ptr[i]  = excl;
      row_fill[i] = excl;
    }
    __syncthreads();
    if (tid == 1023) carry_s = carry + incl;
    __syncthreads();
  }
  if (tid == 0) row_ptr[NN] = carry_s;
}

__global__ __launch_bounds__(256) void fill_kernel(const int* __restrict__ rows,
                                                   const int* __restrict__ cols,
                                                   const float* __restrict__ vals,
                                                   int* __restrict__ row_fill,
                                                   int2* __restrict__ csr_cv) {
  int e = blockIdx.x * 256 + threadIdx.x;
  if (e >= NE) return;
  int r = rows[e];
  int pos = atomicAdd(&row_fill[r], 1);
  csr_cv[pos] = make_int2(cols[e], __float_as_int(vals[e]));
}

// ============== fused SpMM + residual + dropout + acc ==============
// 32 lanes per row; lane owns float4 of the feature dim.
// MODE 0: acc = x_row + h (x==q, init fused);   writes prev_out
// MODE 1: acc += h;                             writes prev_out
// MODE 2: acc = (acc + h) * 0.25;               no prev write
template <int MODE>
__global__ __launch_bounds__(256) void spmm_layer_kernel(
    const int* __restrict__ row_ptr,
    const int2* __restrict__ csr_cv,
    const float* __restrict__ x,
    float* __restrict__ prev_out,
    float* __restrict__ acc,
    uint32_t kA, uint32_t kB) {
  int r = blockIdx.x * 8 + (threadIdx.x >> 5);
  if (r >= NN) return;
  int lane = threadIdx.x & 31;
  int beg = row_ptr[r], end = row_ptr[r + 1];
  const float4* xv = reinterpret_cast<const float4*>(x);
  float4 s = make_float4(0.f, 0.f, 0.f, 0.f);
  for (int j = beg; j < end; ++j) {
    int2 cv = csr_cv[j];                 // 8B broadcast within the 32-lane group
    float v = __int_as_float(cv.y);
    float4 t = xv[cv.x * 32 + lane];     // 512B coalesced gather per group
    s.x += v * t.x; s.y += v * t.y; s.z += v * t.z; s.w += v * t.w;
  }
  int oi = r * 32 + lane;
  float4 p = xv[oi];                     // residual = prev layer's row
  uint32_t base = (uint32_t)r * 128u + (uint32_t)lane * 4u;
  float sv[4] = {s.x, s.y, s.z, s.w};
  float pv[4] = {p.x, p.y, p.z, p.w};
  float h[4];
#pragma unroll
  for (int j = 0; j < 4; ++j) {
    float t = sv[j] + pv[j];
    h[j] = keep_elem(kA, kB, base + (uint32_t)j) ? t * (1.0f / 0.9f) : 0.0f;
  }
  float4* accv = reinterpret_cast<float4*>(acc);
  if (MODE == 0) {
    accv[oi] = make_float4(pv[0] + h[0], pv[1] + h[1], pv[2] + h[2], pv[3] + h[3]);
    reinterpret_cast<float4*>(prev_out)[oi] = make_float4(h[0], h[1], h[2], h[3]);
  } else if (MODE == 1) {
    float4 a = accv[oi];
    accv[oi] = make_float4(a.x + h[0], a.y + h[1], a.z + h[2], a.w + h[3]);
    reinterpret_cast<float4*>(prev_out)[oi] = make_float4(h[0], h[1], h[2], h[3]);
  } else {
    float4 a = accv[oi];
    accv[oi] = make_float4((a.x + h[0]) * 0.25f, (a.y + h[1]) * 0.25f,
                           (a.z + h[2]) * 0.25f, (a.w + h[3]) * 0.25f);
  }
}

// ======================= fallback (round-2 atomic path) =======================
__global__ __launch_bounds__(256) void init_kernel(const float4* __restrict__ q,
                                                   float4* __restrict__ prev,
                                                   float4* __restrict__ acc,
                                                   float4* __restrict__ S) {
  int i = blockIdx.x * 256 + threadIdx.x;
  if (i < NELEM / 4) {
    float4 v = q[i];
    prev[i] = v; acc[i] = v;
    S[i] = make_float4(0.f, 0.f, 0.f, 0.f);
  }
}

__global__ __launch_bounds__(256) void scatter_kernel(const int* __restrict__ rows,
                                                      const int* __restrict__ cols,
                                                      const float* __restrict__ vals,
                                                      const float* __restrict__ x,
                                                      float* __restrict__ S) {
  int lane = threadIdx.x & 31;
  int e = blockIdx.x * 8 + (threadIdx.x >> 5);
  if (e >= NE) return;
  int r = rows[e]; int c = cols[e]; float v = vals[e];
  const float4* xr = reinterpret_cast<const float4*>(x + (size_t)c * DF);
  float4 xv = xr[lane];
  float* o = S + (size_t)r * DF + lane * 4;
  unsafeAtomicAdd(o + 0, xv.x * v);
  unsafeAtomicAdd(o + 1, xv.y * v);
  unsafeAtomicAdd(o + 2, xv.z * v);
  unsafeAtomicAdd(o + 3, xv.w * v);
}

template <bool LAST>
__global__ __launch_bounds__(256) void layer_kernel(float4* __restrict__ S,
                                                    float4* __restrict__ prev,
                                                    float4* __restrict__ acc,
                                                    uint32_t kA, uint32_t kB) {
  int i = blockIdx.x * 256 + threadIdx.x;
  if (i >= NELEM / 4) return;
  float4 s = S[i]; float4 p = prev[i]; float4 a = acc[i];
  uint32_t base = (uint32_t)i * 4u;
  float sv[4] = {s.x, s.y, s.z, s.w};
  float pv[4] = {p.x, p.y, p.z, p.w};
  float h[4];
#pragma unroll
  for (int j = 0; j < 4; ++j) {
    float t = sv[j] + pv[j];
    h[j] = keep_elem(kA, kB, base + (uint32_t)j) ? t * (1.0f / 0.9f) : 0.0f;
  }
  a.x += h[0]; a.y += h[1]; a.z += h[2]; a.w += h[3];
  if (LAST) { a.x *= 0.25f; a.y *= 0.25f; a.z *= 0.25f; a.w *= 0.25f; }
  acc[i] = a;
  prev[i] = make_float4(h[0], h[1], h[2], h[3]);
  S[i] = make_float4(0.f, 0.f, 0.f, 0.f);
}

// ======================= launch =======================
extern "C" void kernel_launch(void* const* d_in, const int* in_sizes, int n_in,
                              void* d_out, int out_size, void* d_ws, size_t ws_size,
                              hipStream_t stream) {
  const float* q   = (const float*)d_in[0];
  const int* rows  = (const int*)d_in[1];
  const int* cols  = (const int*)d_in[2];
  const float* vls = (const float*)d_in[3];
  float* acc = (float*)d_out;

  // layer keys: fold_in(key(42), layer) = threefry2x32((0,42),(0,layer))
  uint32_t kA[3], kB[3];
  for (int l = 0; l < 3; ++l) {
    uint32_t x0 = 0u, x1 = (uint32_t)l;
    tf2x32(x0, x1, 0u, 42u);
    kA[l] = x0; kB[l] = x1;
  }

  const size_t need_csr = (size_t)2 * NELEM * 4 + (size_t)NE * 8 + ((size_t)3 * NN + 1) * 4;
  dim3 blk(256);

  if (ws_size >= need_csr) {
    float* hbuf0   = (float*)d_ws;                 // layer-0 output h1
    float* hbuf1   = hbuf0 + NELEM;                // layer-1 output h2
    int2*  csr_cv  = (int2*)(hbuf1 + NELEM);       // NE (col, val) pairs
    int*   row_ptr = (int*)(csr_cv + NE);          // NN+1
    int*   row_cnt = row_ptr + NN + 1;             // NN
    int*   row_fill = row_cnt + NN;                // NN

    // CSR build
    zero_cnt_kernel<<<(NN + 255) / 256, blk, 0, stream>>>(row_cnt);
    hist_kernel<<<NE / 256, blk, 0, stream>>>(rows, row_cnt);
    scan_kernel<<<1, 1024, 0, stream>>>(row_cnt, row_ptr, row_fill);
    fill_kernel<<<NE / 256, blk, 0, stream>>>(rows, cols, vls, row_fill, csr_cv);

    const int grid = (NN + 7) / 8;
    spmm_layer_kernel<0><<<grid, blk, 0, stream>>>(row_ptr, csr_cv, q,     hbuf0, acc, kA[0], kB[0]);
    spmm_layer_kernel<1><<<grid, blk, 0, stream>>>(row_ptr, csr_cv, hbuf0, hbuf1, acc, kA[1], kB[1]);
    spmm_layer_kernel<2><<<grid, blk, 0, stream>>>(row_ptr, csr_cv, hbuf1, nullptr, acc, kA[2], kB[2]);
  } else {
    // fallback: round-2 atomic-scatter path (needs 102.4MB)
    float* prev = (float*)d_ws;
    float* S    = prev + NELEM;
    init_kernel<<<NELEM / 4 / 256, blk, 0, stream>>>(
        (const float4*)q, (float4*)prev, (float4*)acc, (float4*)S);
    for (int l = 0; l < 3; ++l) {
      scatter_kernel<<<NE / 8, blk, 0, stream>>>(rows, cols, vls, prev, S);
      if (l < 2)
        layer_kernel<false><<<NELEM / 4 / 256, blk, 0, stream>>>(
            (float4*)S, (float4*)prev, (float4*)acc, kA[l], kB[l]);
      else
        layer_kernel<true><<<NELEM / 4 / 256, blk, 0, stream>>>(
            (float4*)S, (float4*)prev, (float4*)acc, kA[l], kB[l]);
    }
  }
}

// Round 4
// 758.980 us; speedup vs baseline: 21.2435x; 1.6924x over previous
//
#include <hip/hip_runtime.h>
#include <stdint.h>

#define NN 100000
#define DF 128
#define NE 3200000
#define NELEM (NN * DF)          // 12,800,000
#define NBLK ((NN + 255) / 256)  // 391

// ---------------- Threefry-2x32 (JAX-exact, partitionable, bits = x0^x1) ----
__host__ __device__ __forceinline__ void tf2x32(uint32_t& x0, uint32_t& x1,
                                                uint32_t k0, uint32_t k1) {
  uint32_t ks2 = k0 ^ k1 ^ 0x1BD11BDAu;
  x0 += k0; x1 += k1;
#define TF_RND(r) { x0 += x1; x1 = (x1 << (r)) | (x1 >> (32 - (r))); x1 ^= x0; }
  TF_RND(13) TF_RND(15) TF_RND(26) TF_RND(6)
  x0 += k1;  x1 += ks2 + 1u;
  TF_RND(17) TF_RND(29) TF_RND(16) TF_RND(24)
  x0 += ks2; x1 += k0 + 2u;
  TF_RND(13) TF_RND(15) TF_RND(26) TF_RND(6)
  x0 += k0;  x1 += k1 + 3u;
  TF_RND(17) TF_RND(29) TF_RND(16) TF_RND(24)
  x0 += k1;  x1 += ks2 + 4u;
  TF_RND(13) TF_RND(15) TF_RND(26) TF_RND(6)
  x0 += ks2; x1 += k0 + 5u;
#undef TF_RND
}

__device__ __forceinline__ bool keep_elem(uint32_t kA, uint32_t kB, uint32_t idx) {
  uint32_t x0 = 0u, x1 = idx;          // counter = (hi=0, lo=i)
  tf2x32(x0, x1, kA, kB);
  uint32_t bits = x0 ^ x1;             // partitionable combine (verified r2)
  float u = __uint_as_float((bits >> 9) | 0x3f800000u) - 1.0f;
  return u < 0.9f;
}

// ---------------- bf16 helpers (internal compression only) ----------------
__device__ __forceinline__ float bf2f(uint16_t u) {
  return __uint_as_float(((uint32_t)u) << 16);
}
__device__ __forceinline__ uint16_t f2bf(float f) {  // round-to-nearest-even
  uint32_t x = __float_as_uint(f);
  uint32_t r = x + 0x7fffu + ((x >> 16) & 1u);
  return (uint16_t)(r >> 16);
}

// ======================= CSR build =======================
__global__ __launch_bounds__(256) void hist_kernel(const int4* __restrict__ rows4,
                                                   int* __restrict__ cnt) {
  int e = blockIdx.x * 256 + threadIdx.x;   // e indexes groups of 4 edges
  if (e < NE / 4) {
    int4 r = rows4[e];
    atomicAdd(&cnt[r.x], 1);
    atomicAdd(&cnt[r.y], 1);
    atomicAdd(&cnt[r.z], 1);
    atomicAdd(&cnt[r.w], 1);
  }
}

__global__ __launch_bounds__(256) void blocksum_kernel(const int* __restrict__ cnt,
                                                       int* __restrict__ bsum) {
  __shared__ int lds[256];
  int i = blockIdx.x * 256 + threadIdx.x;
  lds[threadIdx.x] = (i < NN) ? cnt[i] : 0;
  __syncthreads();
#pragma unroll
  for (int off = 128; off > 0; off >>= 1) {
    if (threadIdx.x < off) lds[threadIdx.x] += lds[threadIdx.x + off];
    __syncthreads();
  }
  if (threadIdx.x == 0) bsum[blockIdx.x] = lds[0];
}

__global__ __launch_bounds__(512) void scan_bsums_kernel(const int* __restrict__ bsum,
                                                         int* __restrict__ boff) {
  __shared__ int lds[512];
  int tid = threadIdx.x;
  int v = (tid < NBLK) ? bsum[tid] : 0;
  lds[tid] = v;
  __syncthreads();
#pragma unroll
  for (int off = 1; off < 512; off <<= 1) {
    int add = (tid >= off) ? lds[tid - off] : 0;
    __syncthreads();
    lds[tid] += add;
    __syncthreads();
  }
  if (tid < NBLK) boff[tid] = lds[tid] - v;   // exclusive
}

__global__ __launch_bounds__(256) void localscan_kernel(const int* __restrict__ cnt,
                                                        const int* __restrict__ boff,
                                                        int* __restrict__ row_ptr,
                                                        int* __restrict__ row_fill) {
  __shared__ int lds[256];
  int i = blockIdx.x * 256 + threadIdx.x;
  int v = (i < NN) ? cnt[i] : 0;
  lds[threadIdx.x] = v;
  __syncthreads();
#pragma unroll
  for (int off = 1; off < 256; off <<= 1) {
    int add = (threadIdx.x >= off) ? lds[threadIdx.x - off] : 0;
    __syncthreads();
    lds[threadIdx.x] += add;
    __syncthreads();
  }
  if (i < NN) {
    int excl = boff[blockIdx.x] + lds[threadIdx.x] - v;
    row_ptr[i]  = excl;
    row_fill[i] = excl;
  }
  if (i == 0) row_ptr[NN] = NE;
}

__global__ __launch_bounds__(256) void fill_kernel(const int* __restrict__ rows,
                                                   const int* __restrict__ cols,
                                                   const float* __restrict__ vals,
                                                   int* __restrict__ row_fill,
                                                   int2* __restrict__ csr_cv) {
  int e = blockIdx.x * 256 + threadIdx.x;
  if (e >= NE) return;
  int r = rows[e];
  int pos = atomicAdd(&row_fill[r], 1);
  csr_cv[pos] = make_int2(cols[e], __float_as_int(vals[e]));
}

// ---------------- f32 -> bf16 table convert ----------------
__global__ __launch_bounds__(256) void convert_kernel(const float4* __restrict__ src,
                                                      ushort4* __restrict__ dst) {
  int i = blockIdx.x * 256 + threadIdx.x;
  if (i < NELEM / 4) {
    float4 v = src[i];
    dst[i] = make_ushort4(f2bf(v.x), f2bf(v.y), f2bf(v.z), f2bf(v.w));
  }
}

// ============== fused SpMM + residual + dropout + acc (bf16 gathers) ==============
// 32 lanes per row; lane owns 4 features (bf16x4 = 8B gather per lane).
// MODE 0: residual from q_f32; acc = q + h;      writes h -> hb_out (bf16)
// MODE 1: residual from xb (own row);  acc += h; writes h -> hb_out (bf16)
// MODE 2: residual from xb (own row);  acc = (acc + h) * 0.25; no h write
template <int MODE>
__global__ __launch_bounds__(256) void spmm_layer_kernel(
    const int* __restrict__ row_ptr,
    const int2* __restrict__ csr,
    const ushort4* __restrict__ xb,     // gather table, bf16 [NN][32] x4
    const float4* __restrict__ qf,      // f32 q rows (MODE 0 only)
    ushort4* __restrict__ hb_out,
    float4* __restrict__ accv,
    uint32_t kA, uint32_t kB) {
  int r = blockIdx.x * 8 + (threadIdx.x >> 5);
  if (r >= NN) return;
  int lane = threadIdx.x & 31;
  int beg = row_ptr[r], end = row_ptr[r + 1];

  float4 s = make_float4(0.f, 0.f, 0.f, 0.f);
  int n4 = (end - beg) & ~3;
  int j = beg;
  for (; j < beg + n4; j += 4) {   // 4 independent gathers in flight (MLP)
    int2 cv0 = csr[j + 0];
    int2 cv1 = csr[j + 1];
    int2 cv2 = csr[j + 2];
    int2 cv3 = csr[j + 3];
    ushort4 t0 = xb[(size_t)cv0.x * 32 + lane];
    ushort4 t1 = xb[(size_t)cv1.x * 32 + lane];
    ushort4 t2 = xb[(size_t)cv2.x * 32 + lane];
    ushort4 t3 = xb[(size_t)cv3.x * 32 + lane];
    float v0 = __int_as_float(cv0.y), v1 = __int_as_float(cv1.y);
    float v2 = __int_as_float(cv2.y), v3 = __int_as_float(cv3.y);
    s.x += v0 * bf2f(t0.x); s.y += v0 * bf2f(t0.y); s.z += v0 * bf2f(t0.z); s.w += v0 * bf2f(t0.w);
    s.x += v1 * bf2f(t1.x); s.y += v1 * bf2f(t1.y); s.z += v1 * bf2f(t1.z); s.w += v1 * bf2f(t1.w);
    s.x += v2 * bf2f(t2.x); s.y += v2 * bf2f(t2.y); s.z += v2 * bf2f(t2.z); s.w += v2 * bf2f(t2.w);
    s.x += v3 * bf2f(t3.x); s.y += v3 * bf2f(t3.y); s.z += v3 * bf2f(t3.z); s.w += v3 * bf2f(t3.w);
  }
  for (; j < end; ++j) {
    int2 cv = csr[j];
    float v = __int_as_float(cv.y);
    ushort4 t = xb[(size_t)cv.x * 32 + lane];
    s.x += v * bf2f(t.x); s.y += v * bf2f(t.y); s.z += v * bf2f(t.z); s.w += v * bf2f(t.w);
  }

  int oi = r * 32 + lane;
  float pv[4];
  if (MODE == 0) {
    float4 p = qf[oi];
    pv[0] = p.x; pv[1] = p.y; pv[2] = p.z; pv[3] = p.w;
  } else {
    ushort4 p = xb[oi];
    pv[0] = bf2f(p.x); pv[1] = bf2f(p.y); pv[2] = bf2f(p.z); pv[3] = bf2f(p.w);
  }
  uint32_t base = (uint32_t)r * 128u + (uint32_t)lane * 4u;
  float sv[4] = {s.x, s.y, s.z, s.w};
  float h[4];
#pragma unroll
  for (int k = 0; k < 4; ++k) {
    float t = sv[k] + pv[k];
    h[k] = keep_elem(kA, kB, base + (uint32_t)k) ? t * (1.0f / 0.9f) : 0.0f;
  }
  if (MODE == 0) {
    accv[oi] = make_float4(pv[0] + h[0], pv[1] + h[1], pv[2] + h[2], pv[3] + h[3]);
    hb_out[oi] = make_ushort4(f2bf(h[0]), f2bf(h[1]), f2bf(h[2]), f2bf(h[3]));
  } else if (MODE == 1) {
    float4 a = accv[oi];
    accv[oi] = make_float4(a.x + h[0], a.y + h[1], a.z + h[2], a.w + h[3]);
    hb_out[oi] = make_ushort4(f2bf(h[0]), f2bf(h[1]), f2bf(h[2]), f2bf(h[3]));
  } else {
    float4 a = accv[oi];
    accv[oi] = make_float4((a.x + h[0]) * 0.25f, (a.y + h[1]) * 0.25f,
                           (a.z + h[2]) * 0.25f, (a.w + h[3]) * 0.25f);
  }
}

// ======================= launch =======================
extern "C" void kernel_launch(void* const* d_in, const int* in_sizes, int n_in,
                              void* d_out, int out_size, void* d_ws, size_t ws_size,
                              hipStream_t stream) {
  const float* q   = (const float*)d_in[0];
  const int* rows  = (const int*)d_in[1];
  const int* cols  = (const int*)d_in[2];
  const float* vls = (const float*)d_in[3];
  float* acc = (float*)d_out;

  // layer keys: fold_in(key(42), layer) = threefry2x32((0,42),(0,layer))
  uint32_t kA[3], kB[3];
  for (int l = 0; l < 3; ++l) {
    uint32_t x0 = 0u, x1 = (uint32_t)l;
    tf2x32(x0, x1, 0u, 42u);
    kA[l] = x0; kB[l] = x1;
  }

  // workspace layout (~104 MB; harness provided >=129 MB in r3)
  uint16_t* xb_q = (uint16_t*)d_ws;            // NELEM bf16
  uint16_t* hb1  = xb_q + NELEM;               // NELEM bf16
  uint16_t* hb2  = hb1 + NELEM;                // NELEM bf16
  int2* csr_cv   = (int2*)(hb2 + NELEM);       // NE
  int* row_ptr   = (int*)(csr_cv + NE);        // NN+1
  int* row_cnt   = row_ptr + NN + 1;           // NN
  int* row_fill  = row_cnt + NN;               // NN
  int* bsum      = row_fill + NN;              // NBLK
  int* boff      = bsum + NBLK;                // NBLK

  dim3 blk(256);

  hipMemsetAsync(row_cnt, 0, (size_t)NN * 4, stream);
  convert_kernel<<<NELEM / 4 / 256, blk, 0, stream>>>((const float4*)q, (ushort4*)xb_q);
  hist_kernel<<<NE / 4 / 256, blk, 0, stream>>>((const int4*)rows, row_cnt);
  blocksum_kernel<<<NBLK, blk, 0, stream>>>(row_cnt, bsum);
  scan_bsums_kernel<<<1, 512, 0, stream>>>(bsum, boff);
  localscan_kernel<<<NBLK, blk, 0, stream>>>(row_cnt, boff, row_ptr, row_fill);
  fill_kernel<<<NE / 256, blk, 0, stream>>>(rows, cols, vls, row_fill, csr_cv);

  const int grid = (NN + 7) / 8;
  spmm_layer_kernel<0><<<grid, blk, 0, stream>>>(
      row_ptr, csr_cv, (const ushort4*)xb_q, (const float4*)q,
      (ushort4*)hb1, (float4*)acc, kA[0], kB[0]);
  spmm_layer_kernel<1><<<grid, blk, 0, stream>>>(
      row_ptr, csr_cv, (const ushort4*)hb1, nullptr,
      (ushort4*)hb2, (float4*)acc, kA[1], kB[1]);
  spmm_layer_kernel<2><<<grid, blk, 0, stream>>>(
      row_ptr, csr_cv, (const ushort4*)hb2, nullptr,
      nullptr, (float4*)acc, kA[2], kB[2]);
}